// Round 2
// baseline (190.609 us; speedup 1.0000x reference)
//
#include <hip/hip_runtime.h>
#include <hip/hip_bf16.h>

// Temporal_Aggregation — MFMA bf16, fp32 I/O (MI355X gfx950). Round 11.
//
// Folded math (validated rounds 4-8):
//   Wbig[o][j=k*64+i] = sum_c Wlin[o][c]*Wconv[c][i][0][k]   (bf16 in ws)
//   z[t][o]  = sum_j Vp[t+(j>>6)][j&63] * Wbig[o][j]
//   out[t][o] = relu( z[t-1]+z[t]+z[t+1] (clipped) + m_t*biasC[o] + blin[o] )
//
// Round-11 = round-10 integer-lean code at HALF the per-wave state for 2x
// occupancy (theory: latency-bound at ~16% HBM BW, need more resident waves):
//  - R_ROWS 8 -> 4, grid 2048 -> 4096, LDS 29952 -> 14976 B.
//  - per-wave: acc[6], pre[6], 36 MFMA; peak live ~60 VGPR.
//  - __launch_bounds__(256, 8): force <=64 VGPR -> 8 waves/SIMD = 32
//    waves/CU = 8 blocks/CU co-resident (LDS would allow 10).
//  - value loads issued before (L2-hot) weight/bias loads.
//  - band-sum is unaffected: mt%3 edge masks invariant; block M-range ends
//    exactly at r-boundaries (96 = 4*24), so no cross-block band terms.

typedef __attribute__((ext_vector_type(8))) short short8;
typedef __attribute__((ext_vector_type(8))) __bf16 bf16x8;
typedef __attribute__((ext_vector_type(4))) float f4;

#define R_ROWS 4                 // rows per block
#define VP_STRIDE 72             // 64 + 8 pad shorts
#define V_ROW_ELEMS (26 * VP_STRIDE)   // 1872 shorts (pad + 24 + pad)

__device__ __forceinline__ unsigned short f2bfu(float f) {
    return __bfloat16_as_ushort(__float2bfloat16(f));
}

// ---- Kernel 1: fold conv+linear weights -------------------------------------
// ws bytes: [0,24576) Wbig bf16[64][192]; [24576,24832) biasC f32[64];
//           [24832,25088) blinF f32[64]
__global__ void prep_kernel(const float* __restrict__ Wconv,
                            const float* __restrict__ bconv,
                            const float* __restrict__ Wlin,
                            const float* __restrict__ blin,
                            __hip_bfloat16* __restrict__ wbig,
                            float* __restrict__ biasC,
                            float* __restrict__ blinF) {
    __shared__ float Wl[4096];
    const int tid = threadIdx.x;
    for (int c = tid; c < 4096; c += 256) Wl[c] = Wlin[c];
    __syncthreads();
    int idx = blockIdx.x * 256 + tid;
    if (idx < 64 * 192) {
        int o = idx / 192;
        int j = idx - o * 192;
        int k = j >> 6;
        int i = j & 63;
        float acc = 0.0f;
        for (int c = 0; c < 64; ++c)
            acc += Wl[o * 64 + c] * Wconv[c * 192 + i * 3 + k];
        wbig[o * 192 + j] = __float2bfloat16(acc);
    } else if (idx < 64 * 192 + 64) {
        int o = idx - 64 * 192;
        float acc = 0.0f;
        for (int c = 0; c < 64; ++c)
            acc += Wl[o * 64 + c] * bconv[c];
        biasC[o] = acc;
    } else if (idx < 64 * 192 + 128) {
        int o = idx - (64 * 192 + 64);
        blinF[o] = blin[o];
    }
}

// ---- Kernel 2: fused conv-GEMM + band sum + bias + relu ---------------------
__global__ __launch_bounds__(256, 8) void fused_kernel(
    const float* __restrict__ value,
    const __hip_bfloat16* __restrict__ wbig,
    const float* __restrict__ biasC,
    const float* __restrict__ blinF,
    float* __restrict__ out) {
    __shared__ __align__(16) short Vlds[R_ROWS * V_ROW_ELEMS];   // 14976 B

    const int tid = threadIdx.x;
    const int wave = tid >> 6;            // = N-tile index (16 o-columns)
    const int lane = tid & 63;
    const int lane15 = lane & 15;
    const int quad = lane >> 4;
    const long base_row = (long)blockIdx.x * R_ROWS;

    // ---- stage value: 4 rows x 24x64 fp32 -> bf16 padded LDS ----
    // thread -> (sr, tq, d4) via bit ops; load j covers t = 4j + tq.
    // Issued FIRST: these are the HBM-latency long pole.
    f4 pre[6];
    const int sr = tid >> 6;              // row in block 0..3 (== wave)
    const int tq = (tid >> 4) & 3;        // t mod 4 group
    const int d4 = (tid & 15) << 2;       // float4 column
    {
        const float* vrow = value + base_row * 1536 + sr * 1536 + tq * 64 + d4;
        #pragma unroll
        for (int j = 0; j < 6; ++j)
            pre[j] = *(const f4*)(vrow + j * 256);   // t = 4j+tq
    }

    // ---- B fragments for this wave's N-tile (L2-hot after block 0) ----
    const short* wsrc = (const short*)wbig;
    const int k0 = quad * 8;
    bf16x8 breg[6];
    #pragma unroll
    for (int ks = 0; ks < 6; ++ks)
        breg[ks] = __builtin_bit_cast(bf16x8,
            *(const short8*)(wsrc + (wave * 16 + lane15) * 192 + ks * 32 + k0));

    // bias loads issued early; latency hides under staging + K-loop
    const int o = wave * 16 + lane15;
    const float bc = biasC[o];
    const float bl = blinF[o];

    if (tid < 64) {                        // zero pad rows 0 and 25
        int r = tid >> 4;                  // 0..3
        int which = (tid >> 3) & 1;
        int d8 = (tid & 7) << 3;
        uint4 z; z.x = 0; z.y = 0; z.z = 0; z.w = 0;
        *(uint4*)(Vlds + r * V_ROW_ELEMS + which * (25 * VP_STRIDE) + d8) = z;
    }
    {
        // (t+1) pad row offset; all j-offsets are compile-time immediates
        short* lbase = Vlds + sr * V_ROW_ELEMS + (tq + 1) * VP_STRIDE + d4;
        #pragma unroll
        for (int j = 0; j < 6; ++j) {
            ushort4 u;
            u.x = f2bfu(pre[j].x); u.y = f2bfu(pre[j].y);
            u.z = f2bfu(pre[j].z); u.w = f2bfu(pre[j].w);
            *(ushort4*)(lbase + j * (4 * VP_STRIDE)) = u;
        }
    }
    __syncthreads();

    // ---- K-loop: 6 M-tiles x this wave's N-tile, K=192, pure LDS+MFMA ----
    int aoff[6];
    #pragma unroll
    for (int mt = 0; mt < 6; ++mt) {
        int m = mt * 16 + lane15;          // GEMM row, m = r*24 + s
        int r = m / 24;
        int s = m - r * 24;
        aoff[mt] = r * V_ROW_ELEMS + s * VP_STRIDE;
    }
    f4 acc[6];
    #pragma unroll
    for (int mt = 0; mt < 6; ++mt) {
        f4 zz = {0.f, 0.f, 0.f, 0.f};
        acc[mt] = zz;
    }
    #pragma unroll
    for (int ks = 0; ks < 6; ++ks) {
        int k = ks * 32 + k0;
        int ka = ((k >> 6) * VP_STRIDE) + (k & 63);
        #pragma unroll
        for (int mt = 0; mt < 6; ++mt) {
            bf16x8 a = __builtin_bit_cast(bf16x8,
                *(const short8*)(Vlds + aoff[mt] + ka));
            acc[mt] = __builtin_amdgcn_mfma_f32_16x16x32_bf16(
                a, breg[ks], acc[mt], 0, 0, 0);
        }
    }

    // ---- epilogue: wave-local band sum, bias, relu, store ----
    // C/D layout: col = lane&15, row16 = quad*4 + i  [m89]
    // out offset = base_row*1536 + rowq*64 + o, rowq = mt*16 + quad*4 + i
    // t==0 only possible at i==0; t==23 only at i==3 (rowq === i mod 4).
    // (4mt+quad)%6 selects: t0 at quad==0 (mt%3==0) / quad==2 (mt%3==1);
    //                       t23 at quad==1 (mt%3==1) / quad==3 (mt%3==2).
    const float b3 = 3.0f * bc + bl;
    const float b2 = 2.0f * bc + bl;
    const int srcP = (lane + 48) & 63;    // receive from quad-1
    const int srcN = (lane + 16) & 63;    // receive from quad+1
    float* pbase = out + base_row * 1536 + quad * 256 + o;
    #pragma unroll
    for (int mt = 0; mt < 6; ++mt) {
        const int mtp = (mt > 0) ? mt - 1 : 0;
        const int mtn = (mt < 5) ? mt + 1 : 5;
        // sender pre-selects: quad3 serves wrapped quad0 of same mt with
        // previous M-tile's last row; quad0 serves wrapped quad3 with next
        // M-tile's first row. Garbage only where masked by t0/t23.
        float sendP = (quad == 3) ? acc[mtp][3] : acc[mt][3];
        float sendN = (quad == 0) ? acc[mtn][0] : acc[mt][0];
        float prev0 = __shfl(sendP, srcP, 64);
        float next3 = __shfl(sendN, srcN, 64);
        const int m3 = mt % 3;
        const bool t0  = (m3 == 0) ? (quad == 0)
                       : ((m3 == 1) ? (quad == 2) : false);
        const bool t23 = (m3 == 2) ? (quad == 3)
                       : ((m3 == 1) ? (quad == 1) : false);
        float s0 = acc[mt][0] + acc[mt][1] + (t0  ? b2 : (prev0 + b3));
        float s1 = acc[mt][0] + acc[mt][1] + acc[mt][2] + b3;
        float s2 = acc[mt][1] + acc[mt][2] + acc[mt][3] + b3;
        float s3 = acc[mt][2] + acc[mt][3] + (t23 ? b2 : (next3 + b3));
        float* p = pbase + mt * 1024;     // mt*16*64, compile-time
        p[0]   = fmaxf(s0, 0.0f);
        p[64]  = fmaxf(s1, 0.0f);
        p[128] = fmaxf(s2, 0.0f);
        p[192] = fmaxf(s3, 0.0f);
    }
}

extern "C" void kernel_launch(void* const* d_in, const int* in_sizes, int n_in,
                              void* d_out, int out_size, void* d_ws, size_t ws_size,
                              hipStream_t stream) {
    const float* value = (const float*)d_in[0];
    const float* Wconv = (const float*)d_in[1];
    const float* bconv = (const float*)d_in[2];
    const float* Wlin  = (const float*)d_in[3];
    const float* blin  = (const float*)d_in[4];
    float* out = (float*)d_out;

    __hip_bfloat16* wbig = (__hip_bfloat16*)d_ws;
    float* biasC = (float*)((char*)d_ws + 24576);
    float* blinF = (float*)((char*)d_ws + 24832);

    prep_kernel<<<49, 256, 0, stream>>>(Wconv, bconv, Wlin, blin, wbig, biasC, blinF);
    // 16384 rows / 4 per block = 4096 blocks
    fused_kernel<<<4096, 256, 0, stream>>>(value, wbig, biasC, blinF, out);
}